// Round 15
// baseline (275.577 us; speedup 1.0000x reference)
//
#include <hip/hip_runtime.h>
#include <hip/hip_bf16.h>

// MFW encdec multihead attention, MI355X — all-fp16, v7+nt attn (274.7 µs base)
// + merged KV/Q GEMM dispatch (q16 lives in d_out's outF region until out GEMM
// overwrites it) + nontemporal out-GEMM stores.
// d_out FLOAT32: [out 8.4M | probs 134.2M].

typedef float  fx4 __attribute__((ext_vector_type(4)));
typedef short  sx8 __attribute__((ext_vector_type(8)));
typedef _Float16 hx8 __attribute__((ext_vector_type(8)));

__device__ __forceinline__ unsigned short f2h(float f) {
  return __builtin_bit_cast(unsigned short, (_Float16)f);
}
__device__ __forceinline__ float h2f(unsigned short h) {
  return (float)__builtin_bit_cast(_Float16, h);
}
__device__ __forceinline__ unsigned pk2h(float a, float b) {
  return __builtin_bit_cast(unsigned, __builtin_amdgcn_cvt_pkrtz(a, b));
}

__device__ __forceinline__ void gload_lds16(const void* g, void* l) {
  __builtin_amdgcn_global_load_lds((const __attribute__((address_space(1))) void*)g,
                                   (__attribute__((address_space(3))) void*)l, 16, 0, 0);
}

__device__ __forceinline__ fx4 mfma_h(sx8 a, sx8 b, fx4 c) {
  return __builtin_amdgcn_mfma_f32_16x16x32_f16(__builtin_bit_cast(hx8, a),
                                                __builtin_bit_cast(hx8, b), c, 0, 0, 0);
}

// drain vmem (untracked gload_lds) + sync
__device__ __forceinline__ void wait_vm_bar() {
  __builtin_amdgcn_sched_barrier(0);
  asm volatile("s_waitcnt vmcnt(0)" ::: "memory");
  __builtin_amdgcn_s_barrier();
  __builtin_amdgcn_sched_barrier(0);
}
// LDS-only barrier (global stores stay in flight)
__device__ __forceinline__ void bar_lgkm() {
  __builtin_amdgcn_sched_barrier(0);
  asm volatile("s_waitcnt lgkmcnt(0)" ::: "memory");
  __builtin_amdgcn_s_barrier();
  __builtin_amdgcn_sched_barrier(0);
}

// ---------------------------------------------------------------------------
// Kernel 1 (fused): build adapted weights (fp16) + q/k f32->fp16 conversion.
// blocks 0..16383: weights (gid 0..4M).  blocks 16384..24575: cvt (2M thr x 8).
// ---------------------------------------------------------------------------
__global__ void k_prep(
    const float* wq, const float* wkv, const float* wo,
    const float* r_q, const float* s_q, const float* r_kv, const float* s_kv,
    const float* r_o, const float* s_o,
    const float* rm_q, const float* sm_q, const float* rm_kv, const float* sm_kv,
    const float* rm_o, const float* sm_o,
    const int* src_i, const int* tgt_i,
    unsigned short* Wq16, unsigned short* Wkv16, unsigned short* Wo16,
    const float* query, const float* key,
    unsigned short* qh, unsigned short* kh)
{
  const int gid = blockIdx.x * 256 + threadIdx.x;
  if (gid >= 4194304) {                         // ---- cvt part ----
    const int cid = gid - 4194304;              // 0 .. 2M-1
    const bool isq = cid < 1048576;
    const size_t off = (size_t)(isq ? cid : cid - 1048576) * 8;
    const float* s = (isq ? query : key) + off;
    unsigned short* d = (isq ? qh : kh) + off;
    fx4 a = *(const fx4*)s, bv = *(const fx4*)(s + 4);
    sx8 h;
    #pragma unroll
    for (int j = 0; j < 4; ++j) { h[j] = (short)f2h(a[j]); h[4 + j] = (short)f2h(bv[j]); }
    *(sx8*)d = h;
    return;
  }
  const int it = tgt_i[0], is = src_i[0];
  const int mat = gid >> 20;
  const int idx = gid & 1048575;
  const int o = idx >> 10, i = idx & 1023;
  float lrm = 0.f, lr = 0.f;
  if (mat == 0) {
    #pragma unroll
    for (int r = 0; r < 4; ++r) {
      lrm += rm_q[(it * 4 + r) * 1024 + o] * sm_q[(is * 4 + r) * 1024 + i];
      lr  += r_q [(it * 4 + r) * 1024 + o] * s_q [(is * 4 + r) * 1024 + i];
    }
    Wq16[idx] = f2h((wq[idx] * lrm + lr) * 0.125f);
  } else if (mat == 1) {
    #pragma unroll
    for (int r = 0; r < 4; ++r) {
      lrm += rm_kv[(it * 4 + r) * 2048 + o] * sm_kv[(is * 4 + r) * 1024 + i];
      lr  += r_kv [(it * 4 + r) * 2048 + o] * s_kv [(is * 4 + r) * 1024 + i];
    }
    Wkv16[idx] = f2h(wkv[idx] * lrm + lr);
  } else if (mat == 2) {
    #pragma unroll
    for (int r = 0; r < 4; ++r) {
      lrm += rm_kv[(it * 4 + r) * 2048 + 1024 + o] * sm_kv[(is * 4 + r) * 1024 + i];
      lr  += r_kv [(it * 4 + r) * 2048 + 1024 + o] * s_kv [(is * 4 + r) * 1024 + i];
    }
    Wkv16[1048576 + idx] = f2h(wkv[1048576 + idx] * lrm + lr);
  } else {
    #pragma unroll
    for (int r = 0; r < 4; ++r) {
      lrm += rm_o[(it * 4 + r) * 1024 + o] * sm_o[(is * 4 + r) * 1024 + i];
      lr  += r_o [(it * 4 + r) * 1024 + o] * s_o [(is * 4 + r) * 1024 + i];
    }
    Wo16[idx] = f2h(wo[idx] * lrm + lr);
  }
}

// ---------------------------------------------------------------------------
// Kernel 2a (merged): KV GEMM + Q GEMM in one dispatch.
// grid (24, 64): x<16 -> kv = kh @ Wkv^T (N=2048, split k16/v16);
//                x>=16 -> q = qh @ Wq^T (N=1024, -> q16 in outF region).
// 128x128 tile, BK=32, 4 waves, m97 structure.
// ---------------------------------------------------------------------------
__global__ __launch_bounds__(256, 2) void k_gemm_kvq(
    const unsigned short* qh, const unsigned short* kh,
    const unsigned short* Wq16, const unsigned short* Wkv16,
    unsigned short* k16, unsigned short* v16, unsigned short* q16)
{
  __shared__ unsigned short lds[2][2][4096];
  const int tid = threadIdx.x;
  const int l = tid & 63, wid = tid >> 6;
  const int wr = wid >> 1, wc = wid & 1;
  const bool isKV = blockIdx.x < 16;
  const unsigned short* A = isKV ? kh : qh;
  const unsigned short* B = isKV ? Wkv16 : Wq16;
  const int mBase = blockIdx.y * 128;
  const int nBase = (isKV ? blockIdx.x : (blockIdx.x - 16)) * 128;
  const int brow = tid >> 2, bc8 = (tid & 3) * 8;

  fx4 acc[4][4] = {};

  auto stage = [&](int buf, int kt) {
    const int kB = kt * 32;
    gload_lds16(B + (size_t)(nBase + brow) * 1024 + kB + bc8,      &lds[buf][1][tid * 8]);
    gload_lds16(B + (size_t)(nBase + 64 + brow) * 1024 + kB + bc8, &lds[buf][1][2048 + tid * 8]);
    gload_lds16(A + (size_t)(mBase + brow) * 1024 + kB + bc8,      &lds[buf][0][tid * 8]);
    gload_lds16(A + (size_t)(mBase + 64 + brow) * 1024 + kB + bc8, &lds[buf][0][2048 + tid * 8]);
  };

  auto compute = [&](int buf) {
    sx8 af[4], bfv[4];
    #pragma unroll
    for (int x = 0; x < 4; ++x) {
      af[x]  = *(const sx8*)&lds[buf][0][(wr * 64 + x * 16 + (l & 15)) * 32 + (l >> 4) * 8];
      bfv[x] = *(const sx8*)&lds[buf][1][(wc * 64 + x * 16 + (l & 15)) * 32 + (l >> 4) * 8];
    }
    #pragma unroll
    for (int mi = 0; mi < 4; ++mi)
      #pragma unroll
      for (int ni = 0; ni < 4; ++ni)
        acc[mi][ni] = mfma_h(af[mi], bfv[ni], acc[mi][ni]);
  };

  stage(0, 0);
  __syncthreads();
  for (int kt = 0; kt < 32; ++kt) {
    const int buf = kt & 1;
    if (kt + 1 < 32) stage(buf ^ 1, kt + 1);
    compute(buf);
    __syncthreads();
  }

  #pragma unroll
  for (int mi = 0; mi < 4; ++mi)
    #pragma unroll
    for (int ni = 0; ni < 4; ++ni)
      #pragma unroll
      for (int i = 0; i < 4; ++i) {
        const size_t row = (size_t)(mBase + wr * 64 + mi * 16 + (l >> 4) * 4 + i);
        const int col = nBase + wc * 64 + ni * 16 + (l & 15);
        const unsigned short hv = f2h(acc[mi][ni][i]);
        if (isKV) {
          if (col < 1024) k16[row * 1024 + col] = hv;
          else            v16[row * 1024 + (col - 1024)] = hv;
        } else {
          q16[row * 1024 + col] = hv;
        }
      }
}

// ---------------------------------------------------------------------------
// Kernel 2c: out GEMM: outF = ctx @ Wo^T (f32, NONTEMPORAL stores).
// ---------------------------------------------------------------------------
__global__ __launch_bounds__(256, 2) void k_gemm_out(
    const unsigned short* A, const unsigned short* B, float* Cf)
{
  __shared__ unsigned short lds[2][2][4096];
  const int tid = threadIdx.x;
  const int l = tid & 63, wid = tid >> 6;
  const int wr = wid >> 1, wc = wid & 1;
  const int mBase = blockIdx.y * 128, nBase = blockIdx.x * 128;
  const int brow = tid >> 2, bc8 = (tid & 3) * 8;

  fx4 acc[4][4] = {};

  auto stage = [&](int buf, int kt) {
    const int kB = kt * 32;
    gload_lds16(B + (size_t)(nBase + brow) * 1024 + kB + bc8,      &lds[buf][1][tid * 8]);
    gload_lds16(B + (size_t)(nBase + 64 + brow) * 1024 + kB + bc8, &lds[buf][1][2048 + tid * 8]);
    gload_lds16(A + (size_t)(mBase + brow) * 1024 + kB + bc8,      &lds[buf][0][tid * 8]);
    gload_lds16(A + (size_t)(mBase + 64 + brow) * 1024 + kB + bc8, &lds[buf][0][2048 + tid * 8]);
  };

  auto compute = [&](int buf) {
    sx8 af[4], bfv[4];
    #pragma unroll
    for (int x = 0; x < 4; ++x) {
      af[x]  = *(const sx8*)&lds[buf][0][(wr * 64 + x * 16 + (l & 15)) * 32 + (l >> 4) * 8];
      bfv[x] = *(const sx8*)&lds[buf][1][(wc * 64 + x * 16 + (l & 15)) * 32 + (l >> 4) * 8];
    }
    #pragma unroll
    for (int mi = 0; mi < 4; ++mi)
      #pragma unroll
      for (int ni = 0; ni < 4; ++ni)
        acc[mi][ni] = mfma_h(af[mi], bfv[ni], acc[mi][ni]);
  };

  stage(0, 0);
  __syncthreads();
  for (int kt = 0; kt < 32; ++kt) {
    const int buf = kt & 1;
    if (kt + 1 < 32) stage(buf ^ 1, kt + 1);
    compute(buf);
    __syncthreads();
  }

  #pragma unroll
  for (int mi = 0; mi < 4; ++mi)
    #pragma unroll
    for (int ni = 0; ni < 4; ++ni)
      #pragma unroll
      for (int i = 0; i < 4; ++i) {
        const size_t row = (size_t)(mBase + wr * 64 + mi * 16 + (l >> 4) * 4 + i);
        const int col = nBase + wc * 64 + ni * 16 + (l & 15);
        __builtin_nontemporal_store(acc[mi][ni][i], &Cf[row * 1024 + col]);
      }
}

// ---------------------------------------------------------------------------
// Kernel 2b: per-head V transpose (validated round 6):
// v16[(k*8+b)*1024 + h*64 + d] -> vT[((b*16+h)*64 + d)*1024 + k].
// ---------------------------------------------------------------------------
__global__ __launch_bounds__(256) void k_vt(const unsigned short* v16, unsigned short* vT)
{
  __shared__ unsigned short t[64 * 72];
  const int tid = threadIdx.x;
  const int head = blockIdx.x >> 4, kb = blockIdx.x & 15;
  const int b = head >> 4, hh = head & 15;
  const int kl = tid >> 2, part = tid & 3;
  #pragma unroll
  for (int u = 0; u < 2; ++u) {
    sx8 v = *(const sx8*)&v16[(size_t)((kb * 64 + kl) * 8 + b) * 1024 + hh * 64 + part * 16 + u * 8];
    *(sx8*)&t[kl * 72 + part * 16 + u * 8] = v;
  }
  __syncthreads();
  const int dr = tid >> 2;
  unsigned short out[16];
  #pragma unroll
  for (int j = 0; j < 16; ++j) out[j] = t[(part * 16 + j) * 72 + dr];
  unsigned short* dst = vT + (size_t)((b * 16 + hh) * 64 + dr) * 1024 + kb * 64 + part * 16;
  *(sx8*)dst       = *(sx8*)&out[0];
  *(sx8*)(dst + 8) = *(sx8*)&out[8];
}

// ---------------------------------------------------------------------------
// Kernel 3: FUSED attn v7+nt.  Block = (head, 32 q), 512 thr, 8 waves.
// QK^T/softmax/P-write as validated (waves = (qg, q4)).
// POST-SOFTMAX ROLE-SPLIT (Pl read-only):
//   waves 0-3: ALL of PV.  wave w = d-slice w*16; both q-tiles; V frag shared.
//   waves 4-7: ALL probs f32 conversion + coalesced NONTEMPORAL stores.
// No barriers after the split.  LDS 66.5 KB -> 2 blocks/CU.
// ---------------------------------------------------------------------------
__global__ __launch_bounds__(512, 4) void k_attn(
    const unsigned short* q16, const unsigned short* k16, const unsigned short* vT,
    float* probsF, unsigned short* ctx)
{
  __shared__ __align__(16) unsigned short Pl[32768];   // 64 KB: K chunk, then P
  __shared__ float redm[128], reds[128];               // [q 0..31][quarter]

  const int tid = threadIdx.x, l = tid & 63, wid = tid >> 6;
  const int qg = wid >> 2, q4 = wid & 3;
  const int r = l & 15, g = l >> 4;
  const int bid = blockIdx.x;
  const int logical = (bid & 7) * 512 + (bid >> 3);    // XCD-grouped, bijective
  const int head = logical >> 5, qb = logical & 31;
  const int b = head >> 4, hh = head & 15;

  auto stage_k = [&](int c) {
    #pragma unroll
    for (int rr = 0; rr < 8; ++rr) {
      const int e = rr * 512 + tid;
      const int lk = e >> 3, ch = e & 7;
      gload_lds16(k16 + (size_t)((c * 512 + lk) * 8 + b) * 1024 + hh * 64 + ((ch ^ (lk & 7)) * 8),
                  &Pl[e * 8]);
    }
  };

  // Q fragments (16 q-rows per qg-group)
  sx8 qf0, qf1;
  {
    const int qrow = qb * 32 + qg * 16 + r;
    const size_t qoff = (size_t)(qrow * 8 + b) * 1024 + hh * 64 + g * 8;
    qf0 = *(const sx8*)&q16[qoff];
    qf1 = *(const sx8*)&q16[qoff + 32];
  }

  // ---- QK^T over 2 bulk chunks ---------------------------------------------
  // acc[c*8+t][i] = scores[k = c*512 + q4*128 + t*16 + g*4 + i][q = qg*16 + r]
  fx4 acc[16];
  #pragma unroll
  for (int s = 0; s < 16; ++s) acc[s] = fx4{0.f, 0.f, 0.f, 0.f};

  stage_k(0);
  wait_vm_bar();
  #pragma unroll
  for (int t = 0; t < 8; ++t) {
    const int lk = q4 * 128 + t * 16 + r;
    sx8 kb0 = *(const sx8*)&Pl[lk * 64 + ((g ^ (l & 7))) * 8];
    sx8 kb1 = *(const sx8*)&Pl[lk * 64 + (((4 + g) ^ (l & 7))) * 8];
    acc[t] = mfma_h(kb0, qf0, acc[t]);
    acc[t] = mfma_h(kb1, qf1, acc[t]);
  }
  bar_lgkm();                  // chunk-0 reads retired before overwrite
  stage_k(1);
  wait_vm_bar();
  #pragma unroll
  for (int t = 0; t < 8; ++t) {
    const int lk = q4 * 128 + t * 16 + r;
    sx8 kb0 = *(const sx8*)&Pl[lk * 64 + ((g ^ (l & 7))) * 8];
    sx8 kb1 = *(const sx8*)&Pl[lk * 64 + (((4 + g) ^ (l & 7))) * 8];
    acc[8 + t] = mfma_h(kb0, qf0, acc[8 + t]);
    acc[8 + t] = mfma_h(kb1, qf1, acc[8 + t]);
  }

  // ---- softmax (lane owns q = qg*16 + r; k spread over g and q4) -----------
  const int q = qg * 16 + r;
  float m = -3e38f;
  #pragma unroll
  for (int s = 0; s < 16; ++s)
    #pragma unroll
    for (int i = 0; i < 4; ++i) m = fmaxf(m, acc[s][i]);
  m = fmaxf(m, __shfl_xor(m, 16));
  m = fmaxf(m, __shfl_xor(m, 32));
  if (g == 0) redm[q * 4 + q4] = m;
  bar_lgkm();                  // also: chunk-1 K reads retired
  const float mf = fmaxf(fmaxf(redm[q * 4], redm[q * 4 + 1]),
                         fmaxf(redm[q * 4 + 2], redm[q * 4 + 3]));
  float ssum = 0.f;
  #pragma unroll
  for (int s = 0; s < 16; ++s)
    #pragma unroll
    for (int i = 0; i < 4; ++i) {
      const float e = __expf(acc[s][i] - mf);
      acc[s][i] = e;
      ssum += e;
    }
  ssum += __shfl_xor(ssum, 16);
  ssum += __shfl_xor(ssum, 32);
  if (g == 0) reds[q * 4 + q4] = ssum;
  bar_lgkm();
  const float inv = 1.0f / (reds[q * 4] + reds[q * 4 + 1] +
                            reds[q * 4 + 2] + reds[q * 4 + 3]);

  // ---- P fp16 -> Pl (overwrites K), k-contiguous b64 writes ----------------
  #pragma unroll
  for (int idx = 0; idx < 16; ++idx) {
    const int c = idx >> 3, t = idx & 7;
    const int k0 = c * 512 + q4 * 128 + t * 16 + g * 4;
    uint2 w;
    w.x = pk2h(acc[idx][0] * inv, acc[idx][1] * inv);
    w.y = pk2h(acc[idx][2] * inv, acc[idx][3] * inv);
    *(uint2*)&Pl[q * 1024 + (((k0 >> 3) ^ (q & 7)) << 3) + (k0 & 7)] = w;
  }
  bar_lgkm();                  // P complete; Pl read-only from here

  // ======================= POST-SOFTMAX ROLE-SPLIT ==========================
  if (wid < 4) {
    // ---- PV waves: wave wid = d-slice wid*16, both q-tiles ------------------
    fx4 cacc0 = {}, cacc1 = {};
    const unsigned short* vrow = vT + (size_t)((b * 16 + hh) * 64 + wid * 16 + r) * 1024;
    #pragma unroll
    for (int cc = 0; cc < 32; ++cc) {
      const int k0 = cc * 32 + g * 8;
      sx8 vb  = *(const sx8*)&vrow[k0];
      sx8 pa0 = *(const sx8*)&Pl[(0 * 16 + r) * 1024 + (((k0 >> 3) ^ (r & 7)) << 3)];
      sx8 pa1 = *(const sx8*)&Pl[(16 + r) * 1024 + (((k0 >> 3) ^ ((16 + r) & 7)) << 3)];
      cacc0 = mfma_h(pa0, vb, cacc0);
      cacc1 = mfma_h(pa1, vb, cacc1);
    }
    const int d = wid * 16 + r;
    #pragma unroll
    for (int i = 0; i < 4; ++i) {
      const int q0 = qb * 32 + g * 4 + i;
      const int q1 = qb * 32 + 16 + g * 4 + i;
      ctx[(size_t)(q0 * 8 + b) * 1024 + hh * 64 + d] = f2h(cacc0[i]);
      ctx[(size_t)(q1 * 8 + b) * 1024 + hh * 64 + d] = f2h(cacc1[i]);
    }
  } else {
    // ---- probs waves: wave (wid-4) handles 8 rows, NONTEMPORAL stores -------
    const size_t pbase = (size_t)head * 1048576;
    const int rbase = (wid - 4) * 8;
    #pragma unroll
    for (int i = 0; i < 32; ++i) {
      const int row = rbase + (i >> 2);
      const int col = (i & 3) * 256 + l * 4;
      const int c16 = ((col >> 3) ^ (row & 7));
      const unsigned* raw = (const unsigned*)&Pl[row * 1024 + c16 * 8 + (col & 7)];
      const unsigned r0 = raw[0], r1 = raw[1];
      fx4 o;
      o[0] = h2f((unsigned short)(r0 & 0xffffu)); o[1] = h2f((unsigned short)(r0 >> 16));
      o[2] = h2f((unsigned short)(r1 & 0xffffu)); o[3] = h2f((unsigned short)(r1 >> 16));
      __builtin_nontemporal_store(o, (fx4*)&probsF[pbase + (size_t)(qb * 32 + row) * 1024 + col]);
    }
  }
}

// ---------------------------------------------------------------------------
extern "C" void kernel_launch(void* const* d_in, const int* in_sizes, int n_in,
                              void* d_out, int out_size, void* d_ws, size_t ws_size,
                              hipStream_t stream)
{
  const float* query = (const float*)d_in[0];
  const float* key   = (const float*)d_in[1];
  const float* wq    = (const float*)d_in[2];
  const float* wkv   = (const float*)d_in[3];
  const float* wo    = (const float*)d_in[4];
  const float* r_q   = (const float*)d_in[5];
  const float* s_q   = (const float*)d_in[6];
  const float* r_kv  = (const float*)d_in[7];
  const float* s_kv  = (const float*)d_in[8];
  const float* r_o   = (const float*)d_in[9];
  const float* s_o   = (const float*)d_in[10];
  const float* rm_q  = (const float*)d_in[11];
  const float* sm_q  = (const float*)d_in[12];
  const float* rm_kv = (const float*)d_in[13];
  const float* sm_kv = (const float*)d_in[14];
  const float* rm_o  = (const float*)d_in[15];
  const float* sm_o  = (const float*)d_in[16];
  const int* src_i   = (const int*)d_in[17];
  const int* tgt_i   = (const int*)d_in[18];

  unsigned short* ws16 = (unsigned short*)d_ws;
  const size_t M1 = 1048576, M8 = 8388608;
  unsigned short* Wq16  = ws16;                // 1M
  unsigned short* Wkv16 = ws16 + M1;           // 2M
  unsigned short* Wo16  = ws16 + 3 * M1;       // 1M
  unsigned short* qh    = ws16 + 4 * M1;       // 8M (-> ctx after merged GEMM)
  unsigned short* kh    = ws16 + 12 * M1;      // 8M (-> vT after merged GEMM)
  unsigned short* k16   = ws16 + 20 * M1;      // 8M
  unsigned short* v16   = ws16 + 28 * M1;      // 8M   -> total 36M u16 = 72 MB
  unsigned short* vT  = kh;                    // kh dead after merged GEMM
  unsigned short* ctx = qh;                    // qh dead after merged GEMM

  float* outF   = (float*)d_out;               // out: 8388608 f32
  float* probsF = outF + M8;                   // probs: 134217728 f32
  // q16 lives in the outF region (16 MB of 33.5 MB) until out-GEMM overwrites
  unsigned short* q16 = (unsigned short*)outF;

  // fused weights + cvt
  k_prep<<<dim3(24576), dim3(256), 0, stream>>>(
      wq, wkv, wo, r_q, s_q, r_kv, s_kv, r_o, s_o,
      rm_q, sm_q, rm_kv, sm_kv, rm_o, sm_o, src_i, tgt_i,
      Wq16, Wkv16, Wo16, query, key, qh, kh);

  // merged: kv = key @ Wkv^T (k16/v16) AND q = query @ Wq^T (q16 -> outF region)
  k_gemm_kvq<<<dim3(24, 64), dim3(256), 0, stream>>>(
      qh, kh, Wq16, Wkv16, k16, v16, q16);

  // per-head V transpose -> vT (overwrites kh)
  k_vt<<<dim3(2048), dim3(256), 0, stream>>>(v16, vT);

  // v7+nt attn: 4096 blocks (head, 32-q tile), 2 blocks/CU, role-split tail
  k_attn<<<dim3(4096), dim3(512), 0, stream>>>(q16, k16, vT, probsF, ctx);

  // out = ctx @ Wo^T -> f32 d_out (nt stores; overwrites q16 region)
  k_gemm_out<<<dim3(8, 64), dim3(256), 0, stream>>>(ctx, Wo16, outF);
}

// Round 16
// 272.126 us; speedup vs baseline: 1.0127x; 1.0127x over previous
//
#include <hip/hip_runtime.h>
#include <hip/hip_bf16.h>

// MFW encdec multihead attention, MI355X — all-fp16.
// Round 16 = round 15 + GEMM counted-vmcnt pipeline (stage latency hidden
// under a full compute phase; no vmcnt(0) drain per K-step) + XCD-grouped
// GEMM block swizzle (A-panel L2 locality).
// d_out FLOAT32: [out 8.4M | probs 134.2M].  q16 lives in outF region.

typedef float  fx4 __attribute__((ext_vector_type(4)));
typedef short  sx8 __attribute__((ext_vector_type(8)));
typedef _Float16 hx8 __attribute__((ext_vector_type(8)));

__device__ __forceinline__ unsigned short f2h(float f) {
  return __builtin_bit_cast(unsigned short, (_Float16)f);
}
__device__ __forceinline__ float h2f(unsigned short h) {
  return (float)__builtin_bit_cast(_Float16, h);
}
__device__ __forceinline__ unsigned pk2h(float a, float b) {
  return __builtin_bit_cast(unsigned, __builtin_amdgcn_cvt_pkrtz(a, b));
}

__device__ __forceinline__ void gload_lds16(const void* g, void* l) {
  __builtin_amdgcn_global_load_lds((const __attribute__((address_space(1))) void*)g,
                                   (__attribute__((address_space(3))) void*)l, 16, 0, 0);
}

__device__ __forceinline__ fx4 mfma_h(sx8 a, sx8 b, fx4 c) {
  return __builtin_amdgcn_mfma_f32_16x16x32_f16(__builtin_bit_cast(hx8, a),
                                                __builtin_bit_cast(hx8, b), c, 0, 0, 0);
}

// drain ALL vmem + sync
__device__ __forceinline__ void wait_vm_bar() {
  __builtin_amdgcn_sched_barrier(0);
  asm volatile("s_waitcnt vmcnt(0)" ::: "memory");
  __builtin_amdgcn_s_barrier();
  __builtin_amdgcn_sched_barrier(0);
}
// counted drain: leave 4 loads in flight + sync (T4)
__device__ __forceinline__ void wait_vm4_bar() {
  __builtin_amdgcn_sched_barrier(0);
  asm volatile("s_waitcnt vmcnt(4)" ::: "memory");
  __builtin_amdgcn_s_barrier();
  __builtin_amdgcn_sched_barrier(0);
}
// barrier only (no vm drain)
__device__ __forceinline__ void bar_only() {
  __builtin_amdgcn_sched_barrier(0);
  __builtin_amdgcn_s_barrier();
  __builtin_amdgcn_sched_barrier(0);
}
// LDS-only barrier (global stores stay in flight)
__device__ __forceinline__ void bar_lgkm() {
  __builtin_amdgcn_sched_barrier(0);
  asm volatile("s_waitcnt lgkmcnt(0)" ::: "memory");
  __builtin_amdgcn_s_barrier();
  __builtin_amdgcn_sched_barrier(0);
}

// ---------------------------------------------------------------------------
// Kernel 1 (fused): build adapted weights (fp16) + q/k f32->fp16 conversion.
// ---------------------------------------------------------------------------
__global__ void k_prep(
    const float* wq, const float* wkv, const float* wo,
    const float* r_q, const float* s_q, const float* r_kv, const float* s_kv,
    const float* r_o, const float* s_o,
    const float* rm_q, const float* sm_q, const float* rm_kv, const float* sm_kv,
    const float* rm_o, const float* sm_o,
    const int* src_i, const int* tgt_i,
    unsigned short* Wq16, unsigned short* Wkv16, unsigned short* Wo16,
    const float* query, const float* key,
    unsigned short* qh, unsigned short* kh)
{
  const int gid = blockIdx.x * 256 + threadIdx.x;
  if (gid >= 4194304) {                         // ---- cvt part ----
    const int cid = gid - 4194304;              // 0 .. 2M-1
    const bool isq = cid < 1048576;
    const size_t off = (size_t)(isq ? cid : cid - 1048576) * 8;
    const float* s = (isq ? query : key) + off;
    unsigned short* d = (isq ? qh : kh) + off;
    fx4 a = *(const fx4*)s, bv = *(const fx4*)(s + 4);
    sx8 h;
    #pragma unroll
    for (int j = 0; j < 4; ++j) { h[j] = (short)f2h(a[j]); h[4 + j] = (short)f2h(bv[j]); }
    *(sx8*)d = h;
    return;
  }
  const int it = tgt_i[0], is = src_i[0];
  const int mat = gid >> 20;
  const int idx = gid & 1048575;
  const int o = idx >> 10, i = idx & 1023;
  float lrm = 0.f, lr = 0.f;
  if (mat == 0) {
    #pragma unroll
    for (int r = 0; r < 4; ++r) {
      lrm += rm_q[(it * 4 + r) * 1024 + o] * sm_q[(is * 4 + r) * 1024 + i];
      lr  += r_q [(it * 4 + r) * 1024 + o] * s_q [(is * 4 + r) * 1024 + i];
    }
    Wq16[idx] = f2h((wq[idx] * lrm + lr) * 0.125f);
  } else if (mat == 1) {
    #pragma unroll
    for (int r = 0; r < 4; ++r) {
      lrm += rm_kv[(it * 4 + r) * 2048 + o] * sm_kv[(is * 4 + r) * 1024 + i];
      lr  += r_kv [(it * 4 + r) * 2048 + o] * s_kv [(is * 4 + r) * 1024 + i];
    }
    Wkv16[idx] = f2h(wkv[idx] * lrm + lr);
  } else if (mat == 2) {
    #pragma unroll
    for (int r = 0; r < 4; ++r) {
      lrm += rm_kv[(it * 4 + r) * 2048 + 1024 + o] * sm_kv[(is * 4 + r) * 1024 + i];
      lr  += r_kv [(it * 4 + r) * 2048 + 1024 + o] * s_kv [(is * 4 + r) * 1024 + i];
    }
    Wkv16[1048576 + idx] = f2h(wkv[1048576 + idx] * lrm + lr);
  } else {
    #pragma unroll
    for (int r = 0; r < 4; ++r) {
      lrm += rm_o[(it * 4 + r) * 1024 + o] * sm_o[(is * 4 + r) * 1024 + i];
      lr  += r_o [(it * 4 + r) * 1024 + o] * s_o [(is * 4 + r) * 1024 + i];
    }
    Wo16[idx] = f2h(wo[idx] * lrm + lr);
  }
}

// ---------------------------------------------------------------------------
// Kernel 2a (merged): KV GEMM + Q GEMM in one 1-D dispatch (1536 blocks).
// XCD-grouped: 8 consecutive M-tiles (x all 24 N-tiles) per XCD.
// Counted-vmcnt pipeline: stage(kt+1) drains one full compute phase later.
// ---------------------------------------------------------------------------
__global__ __launch_bounds__(256, 2) void k_gemm_kvq(
    const unsigned short* qh, const unsigned short* kh,
    const unsigned short* Wq16, const unsigned short* Wkv16,
    unsigned short* k16, unsigned short* v16, unsigned short* q16)
{
  __shared__ unsigned short lds[2][2][4096];
  const int tid = threadIdx.x;
  const int l = tid & 63, wid = tid >> 6;
  const int wr = wid >> 1, wc = wid & 1;
  const int bid = blockIdx.x;
  const int logical = (bid & 7) * 192 + (bid >> 3);    // bijective, 1536 blocks
  const int by = logical / 24, bx = logical % 24;
  const bool isKV = bx < 16;
  const unsigned short* A = isKV ? kh : qh;
  const unsigned short* B = isKV ? Wkv16 : Wq16;
  const int mBase = by * 128;
  const int nBase = (isKV ? bx : (bx - 16)) * 128;
  const int brow = tid >> 2, bc8 = (tid & 3) * 8;

  fx4 acc[4][4] = {};

  auto stage = [&](int buf, int kt) {
    const int kB = kt * 32;
    gload_lds16(B + (size_t)(nBase + brow) * 1024 + kB + bc8,      &lds[buf][1][tid * 8]);
    gload_lds16(B + (size_t)(nBase + 64 + brow) * 1024 + kB + bc8, &lds[buf][1][2048 + tid * 8]);
    gload_lds16(A + (size_t)(mBase + brow) * 1024 + kB + bc8,      &lds[buf][0][tid * 8]);
    gload_lds16(A + (size_t)(mBase + 64 + brow) * 1024 + kB + bc8, &lds[buf][0][2048 + tid * 8]);
  };

  auto compute = [&](int buf) {
    sx8 af[4], bfv[4];
    #pragma unroll
    for (int x = 0; x < 4; ++x) {
      af[x]  = *(const sx8*)&lds[buf][0][(wr * 64 + x * 16 + (l & 15)) * 32 + (l >> 4) * 8];
      bfv[x] = *(const sx8*)&lds[buf][1][(wc * 64 + x * 16 + (l & 15)) * 32 + (l >> 4) * 8];
    }
    #pragma unroll
    for (int mi = 0; mi < 4; ++mi)
      #pragma unroll
      for (int ni = 0; ni < 4; ++ni)
        acc[mi][ni] = mfma_h(af[mi], bfv[ni], acc[mi][ni]);
  };

  stage(0, 0);
  for (int kt = 0; kt < 32; ++kt) {
    const int buf = kt & 1;
    if (kt + 1 < 32) {
      stage(buf ^ 1, kt + 1);   // 8 outstanding (stage kt + stage kt+1)
      wait_vm4_bar();           // drain stage(kt) only; stage(kt+1) stays in flight
    } else {
      wait_vm_bar();            // last tile: drain all
    }
    compute(buf);
    bar_only();                 // all waves done reading buf before overwrite
  }

  #pragma unroll
  for (int mi = 0; mi < 4; ++mi)
    #pragma unroll
    for (int ni = 0; ni < 4; ++ni)
      #pragma unroll
      for (int i = 0; i < 4; ++i) {
        const size_t row = (size_t)(mBase + wr * 64 + mi * 16 + (l >> 4) * 4 + i);
        const int col = nBase + wc * 64 + ni * 16 + (l & 15);
        const unsigned short hv = f2h(acc[mi][ni][i]);
        if (isKV) {
          if (col < 1024) k16[row * 1024 + col] = hv;
          else            v16[row * 1024 + (col - 1024)] = hv;
        } else {
          q16[row * 1024 + col] = hv;
        }
      }
}

// ---------------------------------------------------------------------------
// Kernel 2c: out GEMM: outF = ctx @ Wo^T (f32, NONTEMPORAL stores).
// Same counted-vmcnt pipeline + XCD grouping (512 blocks).
// ---------------------------------------------------------------------------
__global__ __launch_bounds__(256, 2) void k_gemm_out(
    const unsigned short* A, const unsigned short* B, float* Cf)
{
  __shared__ unsigned short lds[2][2][4096];
  const int tid = threadIdx.x;
  const int l = tid & 63, wid = tid >> 6;
  const int wr = wid >> 1, wc = wid & 1;
  const int bid = blockIdx.x;
  const int logical = (bid & 7) * 64 + (bid >> 3);     // bijective, 512 blocks
  const int mBase = (logical >> 3) * 128, nBase = (logical & 7) * 128;
  const int brow = tid >> 2, bc8 = (tid & 3) * 8;

  fx4 acc[4][4] = {};

  auto stage = [&](int buf, int kt) {
    const int kB = kt * 32;
    gload_lds16(B + (size_t)(nBase + brow) * 1024 + kB + bc8,      &lds[buf][1][tid * 8]);
    gload_lds16(B + (size_t)(nBase + 64 + brow) * 1024 + kB + bc8, &lds[buf][1][2048 + tid * 8]);
    gload_lds16(A + (size_t)(mBase + brow) * 1024 + kB + bc8,      &lds[buf][0][tid * 8]);
    gload_lds16(A + (size_t)(mBase + 64 + brow) * 1024 + kB + bc8, &lds[buf][0][2048 + tid * 8]);
  };

  auto compute = [&](int buf) {
    sx8 af[4], bfv[4];
    #pragma unroll
    for (int x = 0; x < 4; ++x) {
      af[x]  = *(const sx8*)&lds[buf][0][(wr * 64 + x * 16 + (l & 15)) * 32 + (l >> 4) * 8];
      bfv[x] = *(const sx8*)&lds[buf][1][(wc * 64 + x * 16 + (l & 15)) * 32 + (l >> 4) * 8];
    }
    #pragma unroll
    for (int mi = 0; mi < 4; ++mi)
      #pragma unroll
      for (int ni = 0; ni < 4; ++ni)
        acc[mi][ni] = mfma_h(af[mi], bfv[ni], acc[mi][ni]);
  };

  stage(0, 0);
  for (int kt = 0; kt < 32; ++kt) {
    const int buf = kt & 1;
    if (kt + 1 < 32) {
      stage(buf ^ 1, kt + 1);
      wait_vm4_bar();
    } else {
      wait_vm_bar();
    }
    compute(buf);
    bar_only();
  }

  #pragma unroll
  for (int mi = 0; mi < 4; ++mi)
    #pragma unroll
    for (int ni = 0; ni < 4; ++ni)
      #pragma unroll
      for (int i = 0; i < 4; ++i) {
        const size_t row = (size_t)(mBase + wr * 64 + mi * 16 + (l >> 4) * 4 + i);
        const int col = nBase + wc * 64 + ni * 16 + (l & 15);
        __builtin_nontemporal_store(acc[mi][ni][i], &Cf[row * 1024 + col]);
      }
}

// ---------------------------------------------------------------------------
// Kernel 2b: per-head V transpose (validated round 6):
// v16[(k*8+b)*1024 + h*64 + d] -> vT[((b*16+h)*64 + d)*1024 + k].
// ---------------------------------------------------------------------------
__global__ __launch_bounds__(256) void k_vt(const unsigned short* v16, unsigned short* vT)
{
  __shared__ unsigned short t[64 * 72];
  const int tid = threadIdx.x;
  const int head = blockIdx.x >> 4, kb = blockIdx.x & 15;
  const int b = head >> 4, hh = head & 15;
  const int kl = tid >> 2, part = tid & 3;
  #pragma unroll
  for (int u = 0; u < 2; ++u) {
    sx8 v = *(const sx8*)&v16[(size_t)((kb * 64 + kl) * 8 + b) * 1024 + hh * 64 + part * 16 + u * 8];
    *(sx8*)&t[kl * 72 + part * 16 + u * 8] = v;
  }
  __syncthreads();
  const int dr = tid >> 2;
  unsigned short out[16];
  #pragma unroll
  for (int j = 0; j < 16; ++j) out[j] = t[(part * 16 + j) * 72 + dr];
  unsigned short* dst = vT + (size_t)((b * 16 + hh) * 64 + dr) * 1024 + kb * 64 + part * 16;
  *(sx8*)dst       = *(sx8*)&out[0];
  *(sx8*)(dst + 8) = *(sx8*)&out[8];
}

// ---------------------------------------------------------------------------
// Kernel 3: FUSED attn v7+nt (unchanged from round 14/15 best).
// ---------------------------------------------------------------------------
__global__ __launch_bounds__(512, 4) void k_attn(
    const unsigned short* q16, const unsigned short* k16, const unsigned short* vT,
    float* probsF, unsigned short* ctx)
{
  __shared__ __align__(16) unsigned short Pl[32768];   // 64 KB: K chunk, then P
  __shared__ float redm[128], reds[128];               // [q 0..31][quarter]

  const int tid = threadIdx.x, l = tid & 63, wid = tid >> 6;
  const int qg = wid >> 2, q4 = wid & 3;
  const int r = l & 15, g = l >> 4;
  const int bid = blockIdx.x;
  const int logical = (bid & 7) * 512 + (bid >> 3);    // XCD-grouped, bijective
  const int head = logical >> 5, qb = logical & 31;
  const int b = head >> 4, hh = head & 15;

  auto stage_k = [&](int c) {
    #pragma unroll
    for (int rr = 0; rr < 8; ++rr) {
      const int e = rr * 512 + tid;
      const int lk = e >> 3, ch = e & 7;
      gload_lds16(k16 + (size_t)((c * 512 + lk) * 8 + b) * 1024 + hh * 64 + ((ch ^ (lk & 7)) * 8),
                  &Pl[e * 8]);
    }
  };

  // Q fragments (16 q-rows per qg-group)
  sx8 qf0, qf1;
  {
    const int qrow = qb * 32 + qg * 16 + r;
    const size_t qoff = (size_t)(qrow * 8 + b) * 1024 + hh * 64 + g * 8;
    qf0 = *(const sx8*)&q16[qoff];
    qf1 = *(const sx8*)&q16[qoff + 32];
  }

  // ---- QK^T over 2 bulk chunks ---------------------------------------------
  fx4 acc[16];
  #pragma unroll
  for (int s = 0; s < 16; ++s) acc[s] = fx4{0.f, 0.f, 0.f, 0.f};

  stage_k(0);
  wait_vm_bar();
  #pragma unroll
  for (int t = 0; t < 8; ++t) {
    const int lk = q4 * 128 + t * 16 + r;
    sx8 kb0 = *(const sx8*)&Pl[lk * 64 + ((g ^ (l & 7))) * 8];
    sx8 kb1 = *(const sx8*)&Pl[lk * 64 + (((4 + g) ^ (l & 7))) * 8];
    acc[t] = mfma_h(kb0, qf0, acc[t]);
    acc[t] = mfma_h(kb1, qf1, acc[t]);
  }
  bar_lgkm();                  // chunk-0 reads retired before overwrite
  stage_k(1);
  wait_vm_bar();
  #pragma unroll
  for (int t = 0; t < 8; ++t) {
    const int lk = q4 * 128 + t * 16 + r;
    sx8 kb0 = *(const sx8*)&Pl[lk * 64 + ((g ^ (l & 7))) * 8];
    sx8 kb1 = *(const sx8*)&Pl[lk * 64 + (((4 + g) ^ (l & 7))) * 8];
    acc[8 + t] = mfma_h(kb0, qf0, acc[8 + t]);
    acc[8 + t] = mfma_h(kb1, qf1, acc[8 + t]);
  }

  // ---- softmax (lane owns q = qg*16 + r) -----------------------------------
  const int q = qg * 16 + r;
  float m = -3e38f;
  #pragma unroll
  for (int s = 0; s < 16; ++s)
    #pragma unroll
    for (int i = 0; i < 4; ++i) m = fmaxf(m, acc[s][i]);
  m = fmaxf(m, __shfl_xor(m, 16));
  m = fmaxf(m, __shfl_xor(m, 32));
  if (g == 0) redm[q * 4 + q4] = m;
  bar_lgkm();                  // also: chunk-1 K reads retired
  const float mf = fmaxf(fmaxf(redm[q * 4], redm[q * 4 + 1]),
                         fmaxf(redm[q * 4 + 2], redm[q * 4 + 3]));
  float ssum = 0.f;
  #pragma unroll
  for (int s = 0; s < 16; ++s)
    #pragma unroll
    for (int i = 0; i < 4; ++i) {
      const float e = __expf(acc[s][i] - mf);
      acc[s][i] = e;
      ssum += e;
    }
  ssum += __shfl_xor(ssum, 16);
  ssum += __shfl_xor(ssum, 32);
  if (g == 0) reds[q * 4 + q4] = ssum;
  bar_lgkm();
  const float inv = 1.0f / (reds[q * 4] + reds[q * 4 + 1] +
                            reds[q * 4 + 2] + reds[q * 4 + 3]);

  // ---- P fp16 -> Pl (overwrites K), k-contiguous b64 writes ----------------
  #pragma unroll
  for (int idx = 0; idx < 16; ++idx) {
    const int c = idx >> 3, t = idx & 7;
    const int k0 = c * 512 + q4 * 128 + t * 16 + g * 4;
    uint2 w;
    w.x = pk2h(acc[idx][0] * inv, acc[idx][1] * inv);
    w.y = pk2h(acc[idx][2] * inv, acc[idx][3] * inv);
    *(uint2*)&Pl[q * 1024 + (((k0 >> 3) ^ (q & 7)) << 3) + (k0 & 7)] = w;
  }
  bar_lgkm();                  // P complete; Pl read-only from here

  // ======================= POST-SOFTMAX ROLE-SPLIT ==========================
  if (wid < 4) {
    // ---- PV waves: wave wid = d-slice wid*16, both q-tiles ------------------
    fx4 cacc0 = {}, cacc1 = {};
    const unsigned short* vrow = vT + (size_t)((b * 16 + hh) * 64 + wid * 16 + r) * 1024;
    #pragma unroll
    for (int cc = 0; cc < 32; ++cc) {
      const int k0 = cc * 32 + g * 8;
      sx8 vb  = *(const sx8*)&vrow[k0];
      sx8 pa0 = *(const sx8*)&Pl[(0 * 16 + r) * 1024 + (((k0 >> 3) ^ (r & 7)) << 3)];
      sx8 pa1 = *(const sx8*)&Pl[(16 + r) * 1024 + (((k0 >> 3) ^ ((16 + r) & 7)) << 3)];
      cacc0 = mfma_h(pa0, vb, cacc0);
      cacc1 = mfma_h(pa1, vb, cacc1);
    }
    const int d = wid * 16 + r;
    #pragma unroll
    for (int i = 0; i < 4; ++i) {
      const int q0 = qb * 32 + g * 4 + i;
      const int q1 = qb * 32 + 16 + g * 4 + i;
      ctx[(size_t)(q0 * 8 + b) * 1024 + hh * 64 + d] = f2h(cacc0[i]);
      ctx[(size_t)(q1 * 8 + b) * 1024 + hh * 64 + d] = f2h(cacc1[i]);
    }
  } else {
    // ---- probs waves: wave (wid-4) handles 8 rows, NONTEMPORAL stores -------
    const size_t pbase = (size_t)head * 1048576;
    const int rbase = (wid - 4) * 8;
    #pragma unroll
    for (int i = 0; i < 32; ++i) {
      const int row = rbase + (i >> 2);
      const int col = (i & 3) * 256 + l * 4;
      const int c16 = ((col >> 3) ^ (row & 7));
      const unsigned* raw = (const unsigned*)&Pl[row * 1024 + c16 * 8 + (col & 7)];
      const unsigned r0 = raw[0], r1 = raw[1];
      fx4 o;
      o[0] = h2f((unsigned short)(r0 & 0xffffu)); o[1] = h2f((unsigned short)(r0 >> 16));
      o[2] = h2f((unsigned short)(r1 & 0xffffu)); o[3] = h2f((unsigned short)(r1 >> 16));
      __builtin_nontemporal_store(o, (fx4*)&probsF[pbase + (size_t)(qb * 32 + row) * 1024 + col]);
    }
  }
}

// ---------------------------------------------------------------------------
extern "C" void kernel_launch(void* const* d_in, const int* in_sizes, int n_in,
                              void* d_out, int out_size, void* d_ws, size_t ws_size,
                              hipStream_t stream)
{
  const float* query = (const float*)d_in[0];
  const float* key   = (const float*)d_in[1];
  const float* wq    = (const float*)d_in[2];
  const float* wkv   = (const float*)d_in[3];
  const float* wo    = (const float*)d_in[4];
  const float* r_q   = (const float*)d_in[5];
  const float* s_q   = (const float*)d_in[6];
  const float* r_kv  = (const float*)d_in[7];
  const float* s_kv  = (const float*)d_in[8];
  const float* r_o   = (const float*)d_in[9];
  const float* s_o   = (const float*)d_in[10];
  const float* rm_q  = (const float*)d_in[11];
  const float* sm_q  = (const float*)d_in[12];
  const float* rm_kv = (const float*)d_in[13];
  const float* sm_kv = (const float*)d_in[14];
  const float* rm_o  = (const float*)d_in[15];
  const float* sm_o  = (const float*)d_in[16];
  const int* src_i   = (const int*)d_in[17];
  const int* tgt_i   = (const int*)d_in[18];

  unsigned short* ws16 = (unsigned short*)d_ws;
  const size_t M1 = 1048576, M8 = 8388608;
  unsigned short* Wq16  = ws16;                // 1M
  unsigned short* Wkv16 = ws16 + M1;           // 2M
  unsigned short* Wo16  = ws16 + 3 * M1;       // 1M
  unsigned short* qh    = ws16 + 4 * M1;       // 8M (-> ctx after merged GEMM)
  unsigned short* kh    = ws16 + 12 * M1;      // 8M (-> vT after merged GEMM)
  unsigned short* k16   = ws16 + 20 * M1;      // 8M
  unsigned short* v16   = ws16 + 28 * M1;      // 8M   -> total 36M u16 = 72 MB
  unsigned short* vT  = kh;                    // kh dead after merged GEMM
  unsigned short* ctx = qh;                    // qh dead after merged GEMM

  float* outF   = (float*)d_out;               // out: 8388608 f32
  float* probsF = outF + M8;                   // probs: 134217728 f32
  unsigned short* q16 = (unsigned short*)outF; // q16 in outF region until out GEMM

  // fused weights + cvt
  k_prep<<<dim3(24576), dim3(256), 0, stream>>>(
      wq, wkv, wo, r_q, s_q, r_kv, s_kv, r_o, s_o,
      rm_q, sm_q, rm_kv, sm_kv, rm_o, sm_o, src_i, tgt_i,
      Wq16, Wkv16, Wo16, query, key, qh, kh);

  // merged: kv = key @ Wkv^T (k16/v16) AND q = query @ Wq^T (q16 -> outF region)
  k_gemm_kvq<<<dim3(1536), dim3(256), 0, stream>>>(
      qh, kh, Wq16, Wkv16, k16, v16, q16);

  // per-head V transpose -> vT (overwrites kh)
  k_vt<<<dim3(2048), dim3(256), 0, stream>>>(v16, vT);

  // v7+nt attn: 4096 blocks (head, 32-q tile), 2 blocks/CU, role-split tail
  k_attn<<<dim3(4096), dim3(512), 0, stream>>>(q16, k16, vT, probsF, ctx);

  // out = ctx @ Wo^T -> f32 d_out (nt stores; overwrites q16 region)
  k_gemm_out<<<dim3(512), dim3(256), 0, stream>>>(ctx, Wo16, outF);
}